// Round 20
// baseline (378.270 us; speedup 1.0000x reference)
//
#include <hip/hip_runtime.h>
#include <math.h>

#define S_LEN 2048
#define EDIM  2048
#define HDIM  128

typedef __attribute__((ext_vector_type(8))) __bf16 bf16x8;
typedef __attribute__((ext_vector_type(4))) __bf16 bf16x4;
typedef __attribute__((ext_vector_type(4))) float  f32x4;

__device__ __forceinline__ f32x4 mfma16x16x32(bf16x8 a, bf16x8 b, f32x4 c) {
  return __builtin_amdgcn_mfma_f32_16x16x32_bf16(a, b, c, 0, 0, 0);
}

__device__ __forceinline__ void gload_lds16(const __bf16* g, __bf16* l) {
  __builtin_amdgcn_global_load_lds(
      (const __attribute__((address_space(1))) void*)g,
      (__attribute__((address_space(3))) void*)l, 16, 0, 0);
}

// ---------------- dtype probe (zero + count fused; single block)
__global__ void probe_dtype(const unsigned int* __restrict__ x, int* __restrict__ flag) {
  const int tid = threadIdx.x;
  if (tid == 0) *flag = 0;
  __syncthreads();
  int cnt = 0;
  for (int i = tid; i < 4096; i += 256) {
    unsigned e = (x[i] >> 7) & 0xFFu;
    cnt += (e >= 110u && e <= 135u) ? 1 : 0;
  }
  #pragma unroll
  for (int m = 1; m < 64; m <<= 1) cnt += __shfl_xor(cnt, m, 64);
  if ((tid & 63) == 0) atomicAdd(flag, cnt);
}

// ---------------- x -> bf16 (convert only if f32; bf16 path skips entirely)
__global__ __launch_bounds__(256) void xconv(const void* __restrict__ xv,
                                             __bf16* __restrict__ xb,
                                             const int* __restrict__ flag) {
  if (*flag > 2048) return;              // bf16 input: GEMM reads x directly
  const size_t base = ((size_t)blockIdx.x * 256 + threadIdx.x) * 8;
  const float* xf = (const float*)xv + base;
  float4 f0 = *(const float4*)(xf);
  float4 f1 = *(const float4*)(xf + 4);
  bf16x8 v;
  v[0] = (__bf16)f0.x; v[1] = (__bf16)f0.y; v[2] = (__bf16)f0.z; v[3] = (__bf16)f0.w;
  v[4] = (__bf16)f1.x; v[5] = (__bf16)f1.y; v[6] = (__bf16)f1.z; v[7] = (__bf16)f1.w;
  *(bf16x8*)(xb + base) = v;
}

// ---------------- merged QKV weight transpose: one launch, 3 segments.
// WT rows: [0,2048)=wq^T, [2048,2560)=wk^T, [2560,3072)=wv^T; Kd=2048.
__global__ __launch_bounds__(256) void trans_w3(
    const void* __restrict__ wq, const void* __restrict__ wk,
    const void* __restrict__ wv, __bf16* __restrict__ WT,
    const int* __restrict__ flag) {
  const bool bf = (*flag > 2048);
  __shared__ __bf16 t[64 * 72];
  const int tid = threadIdx.x;
  const int bx = blockIdx.x;
  const void* Wv; int Nd, nbase, tile;
  if (bx < 32)      { Wv = wq; Nd = 2048; nbase = 0;    tile = bx; }
  else if (bx < 40) { Wv = wk; Nd = 512;  nbase = 2048; tile = bx - 32; }
  else              { Wv = wv; Nd = 512;  nbase = 2560; tile = bx - 40; }
  const int n0 = tile * 64, k0 = blockIdx.y * 64;
  #pragma unroll
  for (int it = 0; it < 2; ++it) {
    int q = tid + it * 256;
    int r = q >> 3, c8 = q & 7;
    size_t gb = (size_t)(k0 + r) * Nd + n0 + c8 * 8;
    bf16x8 v;
    if (bf) {
      v = *(const bf16x8*)((const __bf16*)Wv + gb);
    } else {
      const float* wf = (const float*)Wv + gb;
      float4 f0 = *(const float4*)(wf);
      float4 f1 = *(const float4*)(wf + 4);
      v[0] = (__bf16)f0.x; v[1] = (__bf16)f0.y; v[2] = (__bf16)f0.z; v[3] = (__bf16)f0.w;
      v[4] = (__bf16)f1.x; v[5] = (__bf16)f1.y; v[6] = (__bf16)f1.z; v[7] = (__bf16)f1.w;
    }
    int eo = (c8 * 8) ^ (((r >> 3) & 7) * 8);
    *(bf16x8*)&t[r * 72 + eo] = v;
  }
  __syncthreads();
  #pragma unroll
  for (int it = 0; it < 2; ++it) {
    int q = tid + it * 256;
    int nl = q >> 3, kc = q & 7;
    bf16x8 o;
    #pragma unroll
    for (int i = 0; i < 8; ++i)
      o[i] = t[(kc * 8 + i) * 72 + (nl ^ (kc * 8))];
    *(bf16x8*)(WT + (size_t)(nbase + n0 + nl) * 2048 + k0 + kc * 8) = o;
  }
}

// ---------------- single-weight transpose (wo)
__global__ __launch_bounds__(256) void trans_w(const void* __restrict__ Wv,
                                               __bf16* __restrict__ WT,
                                               int Kd, int Nd,
                                               const int* __restrict__ flag) {
  const bool bf = (*flag > 2048);
  __shared__ __bf16 t[64 * 72];
  const int tid = threadIdx.x;
  const int n0 = blockIdx.x * 64, k0 = blockIdx.y * 64;
  #pragma unroll
  for (int it = 0; it < 2; ++it) {
    int q = tid + it * 256;
    int r = q >> 3, c8 = q & 7;
    size_t gb = (size_t)(k0 + r) * Nd + n0 + c8 * 8;
    bf16x8 v;
    if (bf) {
      v = *(const bf16x8*)((const __bf16*)Wv + gb);
    } else {
      const float* wf = (const float*)Wv + gb;
      float4 f0 = *(const float4*)(wf);
      float4 f1 = *(const float4*)(wf + 4);
      v[0] = (__bf16)f0.x; v[1] = (__bf16)f0.y; v[2] = (__bf16)f0.z; v[3] = (__bf16)f0.w;
      v[4] = (__bf16)f1.x; v[5] = (__bf16)f1.y; v[6] = (__bf16)f1.z; v[7] = (__bf16)f1.w;
    }
    int eo = (c8 * 8) ^ (((r >> 3) & 7) * 8);
    *(bf16x8*)&t[r * 72 + eo] = v;
  }
  __syncthreads();
  #pragma unroll
  for (int it = 0; it < 2; ++it) {
    int q = tid + it * 256;
    int nl = q >> 3, kc = q & 7;
    bf16x8 o;
    #pragma unroll
    for (int i = 0; i < 8; ++i)
      o[i] = t[(kc * 8 + i) * 72 + (nl ^ (kc * 8))];
    *(bf16x8*)(WT + (size_t)(n0 + nl) * Kd + k0 + kc * 8) = o;
  }
}

// ---------------- V transpose: VT[n][k] = SRC[k][off+n]
__global__ __launch_bounds__(256) void trans_v(const __bf16* __restrict__ SRC,
                                               __bf16* __restrict__ VT,
                                               int str, int off) {
  __shared__ __bf16 t[64 * 72];
  const int tid = threadIdx.x;
  const int n0 = blockIdx.x * 64, k0 = blockIdx.y * 64;
  #pragma unroll
  for (int it = 0; it < 2; ++it) {
    int q = tid + it * 256;
    int r = q >> 3, c8 = q & 7;
    bf16x8 v = *(const bf16x8*)(SRC + (size_t)(k0 + r) * str + off + c8 * 8 + n0);
    int eo = (c8 * 8) ^ (((r >> 3) & 7) * 8);
    *(bf16x8*)&t[r * 72 + eo] = v;
  }
  __syncthreads();
  #pragma unroll
  for (int it = 0; it < 2; ++it) {
    int q = tid + it * 256;
    int nl = q >> 3, kc = q & 7;
    bf16x8 o;
    #pragma unroll
    for (int i = 0; i < 8; ++i)
      o[i] = t[(kc * 8 + i) * 72 + (nl ^ (kc * 8))];
    *(bf16x8*)(VT + (size_t)(n0 + nl) * 4096 + k0 + kc * 8) = o;
  }
}

// ---------------- GEMM: 128x128, BK=32, dbuf LDS, counted-vmcnt pipeline,
// source-swizzled staging (r18/r19 form, frozen).
__global__ __launch_bounds__(256) void gemm_tt(
    const __bf16* __restrict__ A, const void* __restrict__ Araw,
    const __bf16* __restrict__ BT,
    void* __restrict__ Cv, int M, int N, int Kd,
    const int* __restrict__ flag, int cForceBf)
{
  const bool inBf = (*flag > 2048);
  const bool cbf = cForceBf || inBf;
  const __bf16* Ause = inBf ? (const __bf16*)Araw : A;
  __shared__ __bf16 sa[2 * 128 * 32];
  __shared__ __bf16 sb[2 * 128 * 32];
  const int tid = threadIdx.x;
  const int lane = tid & 63, w = tid >> 6;
  const int l15 = lane & 15, lg = lane >> 4;
  const int wr = w >> 1, wc = w & 1;
  const int m0 = blockIdx.y * 128, n0 = blockIdx.x * 128;
  const int lrow = lane >> 2;
  const int lcol = (((lane & 3) ^ (lrow & 3)) * 8);   // source-swizzled col

  f32x4 acc[4][4];
  #pragma unroll
  for (int i = 0; i < 4; ++i)
    #pragma unroll
    for (int j = 0; j < 4; ++j) acc[i][j] = (f32x4)(0.f);

  const __bf16* Ab = Ause + (size_t)(m0 + w * 32 + lrow) * Kd + lcol;
  const __bf16* Bb = BT   + (size_t)(n0 + w * 32 + lrow) * Kd + lcol;
  const int nK = Kd >> 5;

  #pragma unroll
  for (int c = 0; c < 2; ++c) {
    gload_lds16(Ab + (size_t)(16 * c) * Kd, &sa[(w * 2 + c) * 512]);
    gload_lds16(Bb + (size_t)(16 * c) * Kd, &sb[(w * 2 + c) * 512]);
  }

  for (int j = 0; j < nK; ++j) {
    const int cur = (j & 1) * 4096;
    if (j + 1 < nK) {
      const int nxt = ((j + 1) & 1) * 4096;
      const int k1 = (j + 1) << 5;
      #pragma unroll
      for (int c = 0; c < 2; ++c) {
        gload_lds16(Ab + (size_t)(16 * c) * Kd + k1, &sa[nxt + (w * 2 + c) * 512]);
        gload_lds16(Bb + (size_t)(16 * c) * Kd + k1, &sb[nxt + (w * 2 + c) * 512]);
      }
      asm volatile("s_waitcnt vmcnt(4)" ::: "memory");
    } else {
      asm volatile("s_waitcnt vmcnt(0)" ::: "memory");
    }
    asm volatile("s_barrier" ::: "memory");
    __builtin_amdgcn_sched_barrier(0);

    bf16x8 af[4], bfr[4];
    #pragma unroll
    for (int i = 0; i < 4; ++i) {
      int row = wr * 64 + i * 16 + l15;
      af[i] = *(const bf16x8*)&sa[cur + row * 32 + ((lg ^ (row & 3)) * 8)];
    }
    #pragma unroll
    for (int jj = 0; jj < 4; ++jj) {
      int row = wc * 64 + jj * 16 + l15;
      bfr[jj] = *(const bf16x8*)&sb[cur + row * 32 + ((lg ^ (row & 3)) * 8)];
    }
    #pragma unroll
    for (int i = 0; i < 4; ++i)
      #pragma unroll
      for (int jj = 0; jj < 4; ++jj)
        acc[i][jj] = mfma16x16x32(af[i], bfr[jj], acc[i][jj]);

    __builtin_amdgcn_sched_barrier(0);
    asm volatile("s_barrier" ::: "memory");
  }
  __bf16* Cb = (__bf16*)Cv;
  float*  Cf = (float*)Cv;
  #pragma unroll
  for (int i = 0; i < 4; ++i)
    #pragma unroll
    for (int j = 0; j < 4; ++j)
      #pragma unroll
      for (int r = 0; r < 4; ++r) {
        int row = m0 + wr * 64 + i * 16 + lg * 4 + r;
        int col = n0 + wc * 64 + j * 16 + l15;
        if (cbf) Cb[(size_t)row * N + col] = (__bf16)acc[i][j][r];
        else     Cf[(size_t)row * N + col] = acc[i][j][r];
      }
}

// ---------------- merged RoPE: blocks [0,2048) = Q (16 heads, QSCALE),
// [2048,2560) = K (4 heads, scale 1). Row stride 3072.
__global__ __launch_bounds__(256) void rope2(__bf16* __restrict__ qkv, float qscale)
{
  const int bid = blockIdx.x;
  __bf16* buf; int lognh; float scale; int idx0;
  if (bid < 2048) { buf = qkv;        lognh = 4; scale = qscale; idx0 = bid; }
  else            { buf = qkv + 2048; lognh = 2; scale = 1.0f;  idx0 = bid - 2048; }
  const int idx = idx0 * 256 + threadIdx.x;
  const int g   = idx & 7;
  const int h   = (idx >> 3) & ((1 << lognh) - 1);
  const int row = idx >> (3 + lognh);
  const int t   = row & (S_LEN - 1);
  __bf16* p = buf + (size_t)row * 3072 + h * HDIM + g * 8;
  bf16x8 v0 = *(bf16x8*)(p);
  bf16x8 v1 = *(bf16x8*)(p + 64);
  bf16x8 o0, o1;
  #pragma unroll
  for (int j = 0; j < 8; ++j) {
    int i = g * 8 + j;
    float inv = exp2f(-(float)i * 0.2076205059304601f);
    float ang = (float)t * inv;
    float sn, cs;
    sincosf(ang, &sn, &cs);
    cs *= scale; sn *= scale;
    float x0 = (float)v0[j], x1 = (float)v1[j];
    o0[j] = (__bf16)(x0 * cs - x1 * sn);
    o1[j] = (__bf16)(x1 * cs + x0 * sn);
  }
  *(bf16x8*)(p)      = o0;
  *(bf16x8*)(p + 64) = o1;
}

// ---------------- flash attention: single-buffer K/V + slim swizzled P
// staging -> LDS exactly 40 KB -> 4 blocks/CU. 2-barrier loop + T14
// reg-prefetch, loop-invariant LDS addrs, mask-split softmax.
__device__ __forceinline__ void sm_fixed(
    f32x4 (&st)[4], float& l,
    char* pls, int l15, int lg, int qglob, int kv0, bool diag,
    bf16x8& pa0, bf16x8& pa1)
{
  const int swz = (l15 & 7) << 4;
  float rs = 0.f;
  #pragma unroll
  for (int kt = 0; kt < 4; ++kt) {
    bf16x4 pk;
    #pragma unroll
    for (int r = 0; r < 4; ++r) {
      float s = st[kt][r] - 16.f;
      if (diag && (kv0 + kt * 16 + lg * 4 + r > qglob)) s = -1e30f;
      float e = exp2f(s);
      rs += e;
      pk[r] = (__bf16)e;
    }
    *(bf16x4*)(pls + ((l15 * 128 + kt * 32 + lg * 8) ^ swz)) = pk;
  }
  rs += __shfl_xor(rs, 16, 64);
  rs += __shfl_xor(rs, 32, 64);
  l += rs;
  pa0 = *(const bf16x8*)(pls + ((l15 * 128 + lg * 16) ^ swz));
  pa1 = *(const bf16x8*)(pls + ((l15 * 128 + 64 + lg * 16) ^ swz));
}

__global__ __launch_bounds__(256, 4) void flash_fwd(
    const __bf16* __restrict__ Q, const __bf16* __restrict__ Km,
    const __bf16* __restrict__ VT, __bf16* __restrict__ O, int qkstr)
{
  __shared__ __bf16 ks[64 * 128];      // K tile [kv][d], XOR-swizzled (16 KB)
  __shared__ __bf16 vt[64 * 128];      // V^T tile [d][kv], XOR-swizzled (16 KB)
  __shared__ __bf16 pl[4][16 * 64];    // per-wave P^T, stride 64 + XOR (8 KB)
  const int id = blockIdx.x;
  const int c8b = id & 255, k = id >> 8;
  const int bh = c8b & 31, g = c8b >> 5;
  const int t = (k == 0) ? g : (k == 1) ? (15 - g) : (k == 2) ? (16 + g) : (31 - g);
  const int b  = bh >> 4, h = bh & 15;
  const int kvh = h >> 2;
  const int tid = threadIdx.x;
  const int lane = tid & 63, w = tid >> 6;
  const int l15 = lane & 15, lg = lane >> 4;
  const int q0 = t * 64 + w * 16;
  const int rbase = tid >> 4, colc = tid & 15;   // K staging coords
  const int vd = tid >> 3, vkc = tid & 7;        // V^T staging coords

  const __bf16* kgb = Km + (size_t)(b * S_LEN) * qkstr + kvh * HDIM + colc * 8;
  const __bf16* vgb = VT + (size_t)(kvh * HDIM + vd) * (2 * S_LEN) + b * S_LEN + vkc * 8;

  bf16x8 aq[4];
  {
    const __bf16* qa = Q + (size_t)(b * S_LEN + q0 + l15) * qkstr + h * HDIM + lg * 8;
    #pragma unroll
    for (int c = 0; c < 4; ++c) aq[c] = *(const bf16x8*)(qa + c * 32);
  }
  f32x4 o[8];
  float l = 0.f;
  #pragma unroll
  for (int c = 0; c < 8; ++c) o[c] = (f32x4)(0.f);

  const int rswz = ((l15 & 7) << 4) ^ (((l15 >> 3) & 1) << 6);

  int kbyt[4], vbyt[4];
  #pragma unroll
  for (int it = 0; it < 4; ++it) {
    int krow = rbase + it * 16;
    kbyt[it] = (krow * 256 + colc * 16) ^ (((krow & 7) << 4) ^ (((krow >> 3) & 1) << 6));
    int vrow = vd + it * 32;
    vbyt[it] = (vrow * 128 + vkc * 16) ^ ((vrow & 7) << 4);
  }

  bf16x8 kreg[4], vreg[4];
  #pragma unroll
  for (int it = 0; it < 4; ++it) {
    kreg[it] = *(const bf16x8*)(kgb + (size_t)(rbase + it * 16) * qkstr);
    vreg[it] = *(const bf16x8*)(vgb + (size_t)(it * 32) * (2 * S_LEN));
  }

  for (int j = 0; j <= t; ++j) {
    const int kv0 = j * 64;
    if (j) __syncthreads();
    #pragma unroll
    for (int it = 0; it < 4; ++it) {
      *(bf16x8*)((char*)ks + kbyt[it]) = kreg[it];
      *(bf16x8*)((char*)vt + vbyt[it]) = vreg[it];
    }
    __syncthreads();
    if (j < t) {
      #pragma unroll
      for (int it = 0; it < 4; ++it) {
        kreg[it] = *(const bf16x8*)(kgb + (size_t)(kv0 + 64 + rbase + it * 16) * qkstr);
        vreg[it] = *(const bf16x8*)(vgb + (size_t)(it * 32) * (2 * S_LEN) + kv0 + 64);
      }
    }

    f32x4 st[4];
    __builtin_amdgcn_s_setprio(1);
    #pragma unroll
    for (int kt = 0; kt < 4; ++kt) {
      st[kt] = (f32x4)(0.f);
      #pragma unroll
      for (int c = 0; c < 4; ++c) {
        int byt = ((kt * 16 + l15) * 256 + c * 64 + lg * 16) ^ rswz;
        bf16x8 kf = *(const bf16x8*)((const char*)ks + byt);
        st[kt] = mfma16x16x32(kf, aq[c], st[kt]);
      }
    }
    __builtin_amdgcn_s_setprio(0);

    bf16x8 pa0, pa1;
    if (j == t)
      sm_fixed(st, l, (char*)&pl[w][0], l15, lg, q0 + l15, kv0, true, pa0, pa1);
    else
      sm_fixed(st, l, (char*)&pl[w][0], l15, lg, q0 + l15, kv0, false, pa0, pa1);

    __builtin_amdgcn_s_setprio(1);
    #pragma unroll
    for (int c = 0; c < 8; ++c) {
      int d0 = c * 16 + l15;
      int byt0 = (d0 * 128 + lg * 16) ^ ((d0 & 7) << 4);
      int byt1 = (d0 * 128 + lg * 16 + 64) ^ ((d0 & 7) << 4);
      bf16x8 bv0 = *(const bf16x8*)((const char*)vt + byt0);
      bf16x8 bv1 = *(const bf16x8*)((const char*)vt + byt1);
      o[c] = mfma16x16x32(pa0, bv0, o[c]);
      o[c] = mfma16x16x32(pa1, bv1, o[c]);
    }
    __builtin_amdgcn_s_setprio(0);
  }

  float lo[4];
  #pragma unroll
  for (int r = 0; r < 4; ++r) lo[r] = __shfl(l, lg * 4 + r, 64);
  #pragma unroll
  for (int c = 0; c < 8; ++c)
    #pragma unroll
    for (int r = 0; r < 4; ++r)
      O[(size_t)(b * S_LEN + q0 + lg * 4 + r) * EDIM + h * HDIM + c * 16 + l15] =
          (__bf16)(o[c][r] / lo[r]);
}

extern "C" void kernel_launch(void* const* d_in, const int* in_sizes, int n_in,
                              void* d_out, int out_size, void* d_ws, size_t ws_size,
                              hipStream_t stream) {
  const void* x  = d_in[0];
  const void* wq = d_in[1];
  const void* wk = d_in[2];
  const void* wv = d_in[3];
  const void* wo = d_in[4];
  char* ws = (char*)d_ws;
  int*    flagp = (int*)ws;
  __bf16* QKVw = (__bf16*)(ws + 1024);                       // 24 MB [4096][3072]
  __bf16* R4   = (__bf16*)(ws + 1024 + (24u << 20));         // 16 MB: xb then Ow
  __bf16* R5   = (__bf16*)(ws + 1024 + (40u << 20));         // 12 MB: B^T scratch
  __bf16* VwT  = R5 + (size_t)2048 * 2048;                   //  4 MB [512][4096]

  const float QSCALE = 1.4426950408889634f * 0.08838834764831845f; // log2e/sqrt(128)
  dim3 blk(256);
  probe_dtype<<<1, blk, 0, stream>>>((const unsigned int*)x, flagp);
  xconv<<<4096, blk, 0, stream>>>(x, R4, flagp);             // no-op if input bf16

  // fused QKV projection: BT = [wq^T; wk^T; wv^T] [3072][2048] (one transpose launch)
  trans_w3<<<dim3(48, 32), blk, 0, stream>>>(wq, wk, wv, R5, flagp);
  gemm_tt<<<dim3(24, 32), blk, 0, stream>>>(R4, x, R5, QKVw, 4096, 3072, 2048, flagp, 1);

  rope2<<<2560, blk, 0, stream>>>(QKVw, QSCALE);                     // Q+K in one launch
  trans_v<<<dim3(8, 64), blk, 0, stream>>>(QKVw, VwT, 3072, 2560);   // V^T [512][4096]

  trans_w<<<dim3(32, 32), blk, 0, stream>>>(wo, R5, EDIM, EDIM, flagp);
  flash_fwd<<<dim3(1024), blk, 0, stream>>>(QKVw, QKVw + 2048, VwT, R4, 3072); // Ow = R4
  gemm_tt<<<dim3(16, 32), blk, 0, stream>>>(R4, R4, R5, d_out, 4096, 2048, 2048, flagp, 0);
}

// Round 21
// 221.311 us; speedup vs baseline: 1.7092x; 1.7092x over previous
//
#include <hip/hip_runtime.h>
#include <math.h>

#define S_LEN 2048
#define EDIM  2048
#define HDIM  128

typedef __attribute__((ext_vector_type(8))) __bf16 bf16x8;
typedef __attribute__((ext_vector_type(4))) __bf16 bf16x4;
typedef __attribute__((ext_vector_type(4))) float  f32x4;

__device__ __forceinline__ f32x4 mfma16x16x32(bf16x8 a, bf16x8 b, f32x4 c) {
  return __builtin_amdgcn_mfma_f32_16x16x32_bf16(a, b, c, 0, 0, 0);
}

__device__ __forceinline__ void gload_lds16(const __bf16* g, __bf16* l) {
  __builtin_amdgcn_global_load_lds(
      (const __attribute__((address_space(1))) void*)g,
      (__attribute__((address_space(3))) void*)l, 16, 0, 0);
}

// ---------------- dtype probe (zero + count fused; single block)
__global__ void probe_dtype(const unsigned int* __restrict__ x, int* __restrict__ flag) {
  const int tid = threadIdx.x;
  if (tid == 0) *flag = 0;
  __syncthreads();
  int cnt = 0;
  for (int i = tid; i < 4096; i += 256) {
    unsigned e = (x[i] >> 7) & 0xFFu;
    cnt += (e >= 110u && e <= 135u) ? 1 : 0;
  }
  #pragma unroll
  for (int m = 1; m < 64; m <<= 1) cnt += __shfl_xor(cnt, m, 64);
  if ((tid & 63) == 0) atomicAdd(flag, cnt);
}

// ---------------- x -> bf16 (convert only if f32; bf16 path skips entirely)
__global__ __launch_bounds__(256) void xconv(const void* __restrict__ xv,
                                             __bf16* __restrict__ xb,
                                             const int* __restrict__ flag) {
  if (*flag > 2048) return;              // bf16 input: GEMM reads x directly
  const size_t base = ((size_t)blockIdx.x * 256 + threadIdx.x) * 8;
  const float* xf = (const float*)xv + base;
  float4 f0 = *(const float4*)(xf);
  float4 f1 = *(const float4*)(xf + 4);
  bf16x8 v;
  v[0] = (__bf16)f0.x; v[1] = (__bf16)f0.y; v[2] = (__bf16)f0.z; v[3] = (__bf16)f0.w;
  v[4] = (__bf16)f1.x; v[5] = (__bf16)f1.y; v[6] = (__bf16)f1.z; v[7] = (__bf16)f1.w;
  *(bf16x8*)(xb + base) = v;
}

// ---------------- merged QKV weight transpose: one launch, 3 segments.
__global__ __launch_bounds__(256) void trans_w3(
    const void* __restrict__ wq, const void* __restrict__ wk,
    const void* __restrict__ wv, __bf16* __restrict__ WT,
    const int* __restrict__ flag) {
  const bool bf = (*flag > 2048);
  __shared__ __bf16 t[64 * 72];
  const int tid = threadIdx.x;
  const int bx = blockIdx.x;
  const void* Wv; int Nd, nbase, tile;
  if (bx < 32)      { Wv = wq; Nd = 2048; nbase = 0;    tile = bx; }
  else if (bx < 40) { Wv = wk; Nd = 512;  nbase = 2048; tile = bx - 32; }
  else              { Wv = wv; Nd = 512;  nbase = 2560; tile = bx - 40; }
  const int n0 = tile * 64, k0 = blockIdx.y * 64;
  #pragma unroll
  for (int it = 0; it < 2; ++it) {
    int q = tid + it * 256;
    int r = q >> 3, c8 = q & 7;
    size_t gb = (size_t)(k0 + r) * Nd + n0 + c8 * 8;
    bf16x8 v;
    if (bf) {
      v = *(const bf16x8*)((const __bf16*)Wv + gb);
    } else {
      const float* wf = (const float*)Wv + gb;
      float4 f0 = *(const float4*)(wf);
      float4 f1 = *(const float4*)(wf + 4);
      v[0] = (__bf16)f0.x; v[1] = (__bf16)f0.y; v[2] = (__bf16)f0.z; v[3] = (__bf16)f0.w;
      v[4] = (__bf16)f1.x; v[5] = (__bf16)f1.y; v[6] = (__bf16)f1.z; v[7] = (__bf16)f1.w;
    }
    int eo = (c8 * 8) ^ (((r >> 3) & 7) * 8);
    *(bf16x8*)&t[r * 72 + eo] = v;
  }
  __syncthreads();
  #pragma unroll
  for (int it = 0; it < 2; ++it) {
    int q = tid + it * 256;
    int nl = q >> 3, kc = q & 7;
    bf16x8 o;
    #pragma unroll
    for (int i = 0; i < 8; ++i)
      o[i] = t[(kc * 8 + i) * 72 + (nl ^ (kc * 8))];
    *(bf16x8*)(WT + (size_t)(nbase + n0 + nl) * 2048 + k0 + kc * 8) = o;
  }
}

// ---------------- single-weight transpose (wo)
__global__ __launch_bounds__(256) void trans_w(const void* __restrict__ Wv,
                                               __bf16* __restrict__ WT,
                                               int Kd, int Nd,
                                               const int* __restrict__ flag) {
  const bool bf = (*flag > 2048);
  __shared__ __bf16 t[64 * 72];
  const int tid = threadIdx.x;
  const int n0 = blockIdx.x * 64, k0 = blockIdx.y * 64;
  #pragma unroll
  for (int it = 0; it < 2; ++it) {
    int q = tid + it * 256;
    int r = q >> 3, c8 = q & 7;
    size_t gb = (size_t)(k0 + r) * Nd + n0 + c8 * 8;
    bf16x8 v;
    if (bf) {
      v = *(const bf16x8*)((const __bf16*)Wv + gb);
    } else {
      const float* wf = (const float*)Wv + gb;
      float4 f0 = *(const float4*)(wf);
      float4 f1 = *(const float4*)(wf + 4);
      v[0] = (__bf16)f0.x; v[1] = (__bf16)f0.y; v[2] = (__bf16)f0.z; v[3] = (__bf16)f0.w;
      v[4] = (__bf16)f1.x; v[5] = (__bf16)f1.y; v[6] = (__bf16)f1.z; v[7] = (__bf16)f1.w;
    }
    int eo = (c8 * 8) ^ (((r >> 3) & 7) * 8);
    *(bf16x8*)&t[r * 72 + eo] = v;
  }
  __syncthreads();
  #pragma unroll
  for (int it = 0; it < 2; ++it) {
    int q = tid + it * 256;
    int nl = q >> 3, kc = q & 7;
    bf16x8 o;
    #pragma unroll
    for (int i = 0; i < 8; ++i)
      o[i] = t[(kc * 8 + i) * 72 + (nl ^ (kc * 8))];
    *(bf16x8*)(WT + (size_t)(n0 + nl) * Kd + k0 + kc * 8) = o;
  }
}

// ---------------- V transpose: VT[n][k] = SRC[k][off+n]
__global__ __launch_bounds__(256) void trans_v(const __bf16* __restrict__ SRC,
                                               __bf16* __restrict__ VT,
                                               int str, int off) {
  __shared__ __bf16 t[64 * 72];
  const int tid = threadIdx.x;
  const int n0 = blockIdx.x * 64, k0 = blockIdx.y * 64;
  #pragma unroll
  for (int it = 0; it < 2; ++it) {
    int q = tid + it * 256;
    int r = q >> 3, c8 = q & 7;
    bf16x8 v = *(const bf16x8*)(SRC + (size_t)(k0 + r) * str + off + c8 * 8 + n0);
    int eo = (c8 * 8) ^ (((r >> 3) & 7) * 8);
    *(bf16x8*)&t[r * 72 + eo] = v;
  }
  __syncthreads();
  #pragma unroll
  for (int it = 0; it < 2; ++it) {
    int q = tid + it * 256;
    int nl = q >> 3, kc = q & 7;
    bf16x8 o;
    #pragma unroll
    for (int i = 0; i < 8; ++i)
      o[i] = t[(kc * 8 + i) * 72 + (nl ^ (kc * 8))];
    *(bf16x8*)(VT + (size_t)(n0 + nl) * 4096 + k0 + kc * 8) = o;
  }
}

// ---------------- GEMM: 128x128, BK=32, dbuf LDS, counted-vmcnt pipeline,
// source-swizzled staging (r18/r19 form, frozen).
__global__ __launch_bounds__(256) void gemm_tt(
    const __bf16* __restrict__ A, const void* __restrict__ Araw,
    const __bf16* __restrict__ BT,
    void* __restrict__ Cv, int M, int N, int Kd,
    const int* __restrict__ flag, int cForceBf)
{
  const bool inBf = (*flag > 2048);
  const bool cbf = cForceBf || inBf;
  const __bf16* Ause = inBf ? (const __bf16*)Araw : A;
  __shared__ __bf16 sa[2 * 128 * 32];
  __shared__ __bf16 sb[2 * 128 * 32];
  const int tid = threadIdx.x;
  const int lane = tid & 63, w = tid >> 6;
  const int l15 = lane & 15, lg = lane >> 4;
  const int wr = w >> 1, wc = w & 1;
  const int m0 = blockIdx.y * 128, n0 = blockIdx.x * 128;
  const int lrow = lane >> 2;
  const int lcol = (((lane & 3) ^ (lrow & 3)) * 8);   // source-swizzled col

  f32x4 acc[4][4];
  #pragma unroll
  for (int i = 0; i < 4; ++i)
    #pragma unroll
    for (int j = 0; j < 4; ++j) acc[i][j] = (f32x4)(0.f);

  const __bf16* Ab = Ause + (size_t)(m0 + w * 32 + lrow) * Kd + lcol;
  const __bf16* Bb = BT   + (size_t)(n0 + w * 32 + lrow) * Kd + lcol;
  const int nK = Kd >> 5;

  #pragma unroll
  for (int c = 0; c < 2; ++c) {
    gload_lds16(Ab + (size_t)(16 * c) * Kd, &sa[(w * 2 + c) * 512]);
    gload_lds16(Bb + (size_t)(16 * c) * Kd, &sb[(w * 2 + c) * 512]);
  }

  for (int j = 0; j < nK; ++j) {
    const int cur = (j & 1) * 4096;
    if (j + 1 < nK) {
      const int nxt = ((j + 1) & 1) * 4096;
      const int k1 = (j + 1) << 5;
      #pragma unroll
      for (int c = 0; c < 2; ++c) {
        gload_lds16(Ab + (size_t)(16 * c) * Kd + k1, &sa[nxt + (w * 2 + c) * 512]);
        gload_lds16(Bb + (size_t)(16 * c) * Kd + k1, &sb[nxt + (w * 2 + c) * 512]);
      }
      asm volatile("s_waitcnt vmcnt(4)" ::: "memory");
    } else {
      asm volatile("s_waitcnt vmcnt(0)" ::: "memory");
    }
    asm volatile("s_barrier" ::: "memory");
    __builtin_amdgcn_sched_barrier(0);

    bf16x8 af[4], bfr[4];
    #pragma unroll
    for (int i = 0; i < 4; ++i) {
      int row = wr * 64 + i * 16 + l15;
      af[i] = *(const bf16x8*)&sa[cur + row * 32 + ((lg ^ (row & 3)) * 8)];
    }
    #pragma unroll
    for (int jj = 0; jj < 4; ++jj) {
      int row = wc * 64 + jj * 16 + l15;
      bfr[jj] = *(const bf16x8*)&sb[cur + row * 32 + ((lg ^ (row & 3)) * 8)];
    }
    #pragma unroll
    for (int i = 0; i < 4; ++i)
      #pragma unroll
      for (int jj = 0; jj < 4; ++jj)
        acc[i][jj] = mfma16x16x32(af[i], bfr[jj], acc[i][jj]);

    __builtin_amdgcn_sched_barrier(0);
    asm volatile("s_barrier" ::: "memory");
  }
  __bf16* Cb = (__bf16*)Cv;
  float*  Cf = (float*)Cv;
  #pragma unroll
  for (int i = 0; i < 4; ++i)
    #pragma unroll
    for (int j = 0; j < 4; ++j)
      #pragma unroll
      for (int r = 0; r < 4; ++r) {
        int row = m0 + wr * 64 + i * 16 + lg * 4 + r;
        int col = n0 + wc * 64 + j * 16 + l15;
        if (cbf) Cb[(size_t)row * N + col] = (__bf16)acc[i][j][r];
        else     Cf[(size_t)row * N + col] = acc[i][j][r];
      }
}

// ---------------- merged RoPE: blocks [0,2048) = Q (QSCALE), rest = K.
__global__ __launch_bounds__(256) void rope2(__bf16* __restrict__ qkv, float qscale)
{
  const int bid = blockIdx.x;
  __bf16* buf; int lognh; float scale; int idx0;
  if (bid < 2048) { buf = qkv;        lognh = 4; scale = qscale; idx0 = bid; }
  else            { buf = qkv + 2048; lognh = 2; scale = 1.0f;  idx0 = bid - 2048; }
  const int idx = idx0 * 256 + threadIdx.x;
  const int g   = idx & 7;
  const int h   = (idx >> 3) & ((1 << lognh) - 1);
  const int row = idx >> (3 + lognh);
  const int t   = row & (S_LEN - 1);
  __bf16* p = buf + (size_t)row * 3072 + h * HDIM + g * 8;
  bf16x8 v0 = *(bf16x8*)(p);
  bf16x8 v1 = *(bf16x8*)(p + 64);
  bf16x8 o0, o1;
  #pragma unroll
  for (int j = 0; j < 8; ++j) {
    int i = g * 8 + j;
    float inv = exp2f(-(float)i * 0.2076205059304601f);
    float ang = (float)t * inv;
    float sn, cs;
    sincosf(ang, &sn, &cs);
    cs *= scale; sn *= scale;
    float x0 = (float)v0[j], x1 = (float)v1[j];
    o0[j] = (__bf16)(x0 * cs - x1 * sn);
    o1[j] = (__bf16)(x1 * cs + x0 * sn);
  }
  *(bf16x8*)(p)      = o0;
  *(bf16x8*)(p + 64) = o1;
}

// ---------------- flash attention (r19-exact, measured 84 us): single-buffer
// K/V, pl stride 72, 2-barrier loop + T14 reg-prefetch, mask-split softmax.
__device__ __forceinline__ void sm_fixed(
    f32x4 (&st)[4], float& l,
    __bf16* pls, int l15, int lg, int qglob, int kv0, bool diag,
    bf16x8& pa0, bf16x8& pa1)
{
  float rs = 0.f;
  #pragma unroll
  for (int kt = 0; kt < 4; ++kt) {
    bf16x4 pk;
    #pragma unroll
    for (int r = 0; r < 4; ++r) {
      float s = st[kt][r] - 16.f;
      if (diag && (kv0 + kt * 16 + lg * 4 + r > qglob)) s = -1e30f;
      float e = exp2f(s);
      rs += e;
      pk[r] = (__bf16)e;
    }
    *(bf16x4*)&pls[l15 * 72 + kt * 16 + lg * 4] = pk;
  }
  rs += __shfl_xor(rs, 16, 64);
  rs += __shfl_xor(rs, 32, 64);
  l += rs;
  pa0 = *(const bf16x8*)&pls[l15 * 72 + lg * 8];
  pa1 = *(const bf16x8*)&pls[l15 * 72 + 32 + lg * 8];
}

__global__ __launch_bounds__(256, 4) void flash_fwd(
    const __bf16* __restrict__ Q, const __bf16* __restrict__ Km,
    const __bf16* __restrict__ VT, __bf16* __restrict__ O, int qkstr)
{
  __shared__ __bf16 ks[64 * 128];      // K tile [kv][d], XOR-swizzled
  __shared__ __bf16 vt[64 * 128];      // V^T tile [d][kv], XOR-swizzled
  __shared__ __bf16 pl[4][16 * 72];    // per-wave P^T staging, stride 72
  const int id = blockIdx.x;
  const int c8b = id & 255, k = id >> 8;
  const int bh = c8b & 31, g = c8b >> 5;
  const int t = (k == 0) ? g : (k == 1) ? (15 - g) : (k == 2) ? (16 + g) : (31 - g);
  const int b  = bh >> 4, h = bh & 15;
  const int kvh = h >> 2;
  const int tid = threadIdx.x;
  const int lane = tid & 63, w = tid >> 6;
  const int l15 = lane & 15, lg = lane >> 4;
  const int q0 = t * 64 + w * 16;
  const int rbase = tid >> 4, colc = tid & 15;   // K staging coords
  const int vd = tid >> 3, vkc = tid & 7;        // V^T staging coords

  const __bf16* kgb = Km + (size_t)(b * S_LEN) * qkstr + kvh * HDIM + colc * 8;
  const __bf16* vgb = VT + (size_t)(kvh * HDIM + vd) * (2 * S_LEN) + b * S_LEN + vkc * 8;

  bf16x8 aq[4];
  {
    const __bf16* qa = Q + (size_t)(b * S_LEN + q0 + l15) * qkstr + h * HDIM + lg * 8;
    #pragma unroll
    for (int c = 0; c < 4; ++c) aq[c] = *(const bf16x8*)(qa + c * 32);
  }
  f32x4 o[8];
  float l = 0.f;
  #pragma unroll
  for (int c = 0; c < 8; ++c) o[c] = (f32x4)(0.f);

  const int rswz = ((l15 & 7) << 4) ^ (((l15 >> 3) & 1) << 6);

  int kbyt[4], vbyt[4];
  #pragma unroll
  for (int it = 0; it < 4; ++it) {
    int krow = rbase + it * 16;
    kbyt[it] = (krow * 256 + colc * 16) ^ (((krow & 7) << 4) ^ (((krow >> 3) & 1) << 6));
    int vrow = vd + it * 32;
    vbyt[it] = (vrow * 128 + vkc * 16) ^ ((vrow & 7) << 4);
  }

  bf16x8 kreg[4], vreg[4];
  #pragma unroll
  for (int it = 0; it < 4; ++it) {
    kreg[it] = *(const bf16x8*)(kgb + (size_t)(rbase + it * 16) * qkstr);
    vreg[it] = *(const bf16x8*)(vgb + (size_t)(it * 32) * (2 * S_LEN));
  }

  for (int j = 0; j <= t; ++j) {
    const int kv0 = j * 64;
    if (j) __syncthreads();
    #pragma unroll
    for (int it = 0; it < 4; ++it) {
      *(bf16x8*)((char*)ks + kbyt[it]) = kreg[it];
      *(bf16x8*)((char*)vt + vbyt[it]) = vreg[it];
    }
    __syncthreads();
    if (j < t) {
      #pragma unroll
      for (int it = 0; it < 4; ++it) {
        kreg[it] = *(const bf16x8*)(kgb + (size_t)(kv0 + 64 + rbase + it * 16) * qkstr);
        vreg[it] = *(const bf16x8*)(vgb + (size_t)(it * 32) * (2 * S_LEN) + kv0 + 64);
      }
    }

    f32x4 st[4];
    __builtin_amdgcn_s_setprio(1);
    #pragma unroll
    for (int kt = 0; kt < 4; ++kt) {
      st[kt] = (f32x4)(0.f);
      #pragma unroll
      for (int c = 0; c < 4; ++c) {
        int byt = ((kt * 16 + l15) * 256 + c * 64 + lg * 16) ^ rswz;
        bf16x8 kf = *(const bf16x8*)((const char*)ks + byt);
        st[kt] = mfma16x16x32(kf, aq[c], st[kt]);
      }
    }
    __builtin_amdgcn_s_setprio(0);

    bf16x8 pa0, pa1;
    if (j == t)
      sm_fixed(st, l, &pl[w][0], l15, lg, q0 + l15, kv0, true, pa0, pa1);
    else
      sm_fixed(st, l, &pl[w][0], l15, lg, q0 + l15, kv0, false, pa0, pa1);

    __builtin_amdgcn_s_setprio(1);
    #pragma unroll
    for (int c = 0; c < 8; ++c) {
      int d0 = c * 16 + l15;
      int byt0 = (d0 * 128 + lg * 16) ^ ((d0 & 7) << 4);
      int byt1 = (d0 * 128 + lg * 16 + 64) ^ ((d0 & 7) << 4);
      bf16x8 bv0 = *(const bf16x8*)((const char*)vt + byt0);
      bf16x8 bv1 = *(const bf16x8*)((const char*)vt + byt1);
      o[c] = mfma16x16x32(pa0, bv0, o[c]);
      o[c] = mfma16x16x32(pa1, bv1, o[c]);
    }
    __builtin_amdgcn_s_setprio(0);
  }

  float lo[4];
  #pragma unroll
  for (int r = 0; r < 4; ++r) lo[r] = __shfl(l, lg * 4 + r, 64);
  #pragma unroll
  for (int c = 0; c < 8; ++c)
    #pragma unroll
    for (int r = 0; r < 4; ++r)
      O[(size_t)(b * S_LEN + q0 + lg * 4 + r) * EDIM + h * HDIM + c * 16 + l15] =
          (__bf16)(o[c][r] / lo[r]);
}

extern "C" void kernel_launch(void* const* d_in, const int* in_sizes, int n_in,
                              void* d_out, int out_size, void* d_ws, size_t ws_size,
                              hipStream_t stream) {
  const void* x  = d_in[0];
  const void* wq = d_in[1];
  const void* wk = d_in[2];
  const void* wv = d_in[3];
  const void* wo = d_in[4];
  char* ws = (char*)d_ws;
  int*    flagp = (int*)ws;
  __bf16* QKVw = (__bf16*)(ws + 1024);                       // 24 MB [4096][3072]
  __bf16* R4   = (__bf16*)(ws + 1024 + (24u << 20));         // 16 MB: xb then Ow
  __bf16* R5   = (__bf16*)(ws + 1024 + (40u << 20));         // 12 MB: B^T scratch
  __bf16* VwT  = R5 + (size_t)2048 * 2048;                   //  4 MB [512][4096]

  const float QSCALE = 1.4426950408889634f * 0.08838834764831845f; // log2e/sqrt(128)
  dim3 blk(256);
  probe_dtype<<<1, blk, 0, stream>>>((const unsigned int*)x, flagp);
  xconv<<<4096, blk, 0, stream>>>(x, R4, flagp);             // no-op if input bf16

  // fused QKV projection: BT = [wq^T; wk^T; wv^T] [3072][2048]
  trans_w3<<<dim3(48, 32), blk, 0, stream>>>(wq, wk, wv, R5, flagp);
  gemm_tt<<<dim3(24, 32), blk, 0, stream>>>(R4, x, R5, QKVw, 4096, 3072, 2048, flagp, 1);

  rope2<<<2560, blk, 0, stream>>>(QKVw, QSCALE);                     // Q+K, one launch
  trans_v<<<dim3(8, 64), blk, 0, stream>>>(QKVw, VwT, 3072, 2560);   // V^T [512][4096]

  trans_w<<<dim3(32, 32), blk, 0, stream>>>(wo, R5, EDIM, EDIM, flagp);
  flash_fwd<<<dim3(1024), blk, 0, stream>>>(QKVw, QKVw + 2048, VwT, R4, 3072); // Ow = R4
  gemm_tt<<<dim3(16, 32), blk, 0, stream>>>(R4, R4, R5, d_out, 4096, 2048, 2048, flagp, 0);
}

// Round 22
// 215.011 us; speedup vs baseline: 1.7593x; 1.0293x over previous
//
#include <hip/hip_runtime.h>
#include <math.h>

#define S_LEN 2048
#define EDIM  2048
#define HDIM  128

typedef __attribute__((ext_vector_type(8))) __bf16 bf16x8;
typedef __attribute__((ext_vector_type(4))) __bf16 bf16x4;
typedef __attribute__((ext_vector_type(4))) float  f32x4;

__device__ __forceinline__ f32x4 mfma16x16x32(bf16x8 a, bf16x8 b, f32x4 c) {
  return __builtin_amdgcn_mfma_f32_16x16x32_bf16(a, b, c, 0, 0, 0);
}

__device__ __forceinline__ void gload_lds16(const __bf16* g, __bf16* l) {
  __builtin_amdgcn_global_load_lds(
      (const __attribute__((address_space(1))) void*)g,
      (__attribute__((address_space(3))) void*)l, 16, 0, 0);
}

// ---------------- dtype probe (zero + count fused; single block)
__global__ void probe_dtype(const unsigned int* __restrict__ x, int* __restrict__ flag) {
  const int tid = threadIdx.x;
  if (tid == 0) *flag = 0;
  __syncthreads();
  int cnt = 0;
  for (int i = tid; i < 4096; i += 256) {
    unsigned e = (x[i] >> 7) & 0xFFu;
    cnt += (e >= 110u && e <= 135u) ? 1 : 0;
  }
  #pragma unroll
  for (int m = 1; m < 64; m <<= 1) cnt += __shfl_xor(cnt, m, 64);
  if ((tid & 63) == 0) atomicAdd(flag, cnt);
}

// ---------------- x -> bf16 (convert only if f32; bf16 path skips entirely)
__global__ __launch_bounds__(256) void xconv(const void* __restrict__ xv,
                                             __bf16* __restrict__ xb,
                                             const int* __restrict__ flag) {
  if (*flag > 2048) return;              // bf16 input: GEMM reads x directly
  const size_t base = ((size_t)blockIdx.x * 256 + threadIdx.x) * 8;
  const float* xf = (const float*)xv + base;
  float4 f0 = *(const float4*)(xf);
  float4 f1 = *(const float4*)(xf + 4);
  bf16x8 v;
  v[0] = (__bf16)f0.x; v[1] = (__bf16)f0.y; v[2] = (__bf16)f0.z; v[3] = (__bf16)f0.w;
  v[4] = (__bf16)f1.x; v[5] = (__bf16)f1.y; v[6] = (__bf16)f1.z; v[7] = (__bf16)f1.w;
  *(bf16x8*)(xb + base) = v;
}

// ---------------- merged QKV weight transpose: one launch, 3 segments.
__global__ __launch_bounds__(256) void trans_w3(
    const void* __restrict__ wq, const void* __restrict__ wk,
    const void* __restrict__ wv, __bf16* __restrict__ WT,
    const int* __restrict__ flag) {
  const bool bf = (*flag > 2048);
  __shared__ __bf16 t[64 * 72];
  const int tid = threadIdx.x;
  const int bx = blockIdx.x;
  const void* Wv; int Nd, nbase, tile;
  if (bx < 32)      { Wv = wq; Nd = 2048; nbase = 0;    tile = bx; }
  else if (bx < 40) { Wv = wk; Nd = 512;  nbase = 2048; tile = bx - 32; }
  else              { Wv = wv; Nd = 512;  nbase = 2560; tile = bx - 40; }
  const int n0 = tile * 64, k0 = blockIdx.y * 64;
  #pragma unroll
  for (int it = 0; it < 2; ++it) {
    int q = tid + it * 256;
    int r = q >> 3, c8 = q & 7;
    size_t gb = (size_t)(k0 + r) * Nd + n0 + c8 * 8;
    bf16x8 v;
    if (bf) {
      v = *(const bf16x8*)((const __bf16*)Wv + gb);
    } else {
      const float* wf = (const float*)Wv + gb;
      float4 f0 = *(const float4*)(wf);
      float4 f1 = *(const float4*)(wf + 4);
      v[0] = (__bf16)f0.x; v[1] = (__bf16)f0.y; v[2] = (__bf16)f0.z; v[3] = (__bf16)f0.w;
      v[4] = (__bf16)f1.x; v[5] = (__bf16)f1.y; v[6] = (__bf16)f1.z; v[7] = (__bf16)f1.w;
    }
    int eo = (c8 * 8) ^ (((r >> 3) & 7) * 8);
    *(bf16x8*)&t[r * 72 + eo] = v;
  }
  __syncthreads();
  #pragma unroll
  for (int it = 0; it < 2; ++it) {
    int q = tid + it * 256;
    int nl = q >> 3, kc = q & 7;
    bf16x8 o;
    #pragma unroll
    for (int i = 0; i < 8; ++i)
      o[i] = t[(kc * 8 + i) * 72 + (nl ^ (kc * 8))];
    *(bf16x8*)(WT + (size_t)(nbase + n0 + nl) * 2048 + k0 + kc * 8) = o;
  }
}

// ---------------- single-weight transpose (wo)
__global__ __launch_bounds__(256) void trans_w(const void* __restrict__ Wv,
                                               __bf16* __restrict__ WT,
                                               int Kd, int Nd,
                                               const int* __restrict__ flag) {
  const bool bf = (*flag > 2048);
  __shared__ __bf16 t[64 * 72];
  const int tid = threadIdx.x;
  const int n0 = blockIdx.x * 64, k0 = blockIdx.y * 64;
  #pragma unroll
  for (int it = 0; it < 2; ++it) {
    int q = tid + it * 256;
    int r = q >> 3, c8 = q & 7;
    size_t gb = (size_t)(k0 + r) * Nd + n0 + c8 * 8;
    bf16x8 v;
    if (bf) {
      v = *(const bf16x8*)((const __bf16*)Wv + gb);
    } else {
      const float* wf = (const float*)Wv + gb;
      float4 f0 = *(const float4*)(wf);
      float4 f1 = *(const float4*)(wf + 4);
      v[0] = (__bf16)f0.x; v[1] = (__bf16)f0.y; v[2] = (__bf16)f0.z; v[3] = (__bf16)f0.w;
      v[4] = (__bf16)f1.x; v[5] = (__bf16)f1.y; v[6] = (__bf16)f1.z; v[7] = (__bf16)f1.w;
    }
    int eo = (c8 * 8) ^ (((r >> 3) & 7) * 8);
    *(bf16x8*)&t[r * 72 + eo] = v;
  }
  __syncthreads();
  #pragma unroll
  for (int it = 0; it < 2; ++it) {
    int q = tid + it * 256;
    int nl = q >> 3, kc = q & 7;
    bf16x8 o;
    #pragma unroll
    for (int i = 0; i < 8; ++i)
      o[i] = t[(kc * 8 + i) * 72 + (nl ^ (kc * 8))];
    *(bf16x8*)(WT + (size_t)(n0 + nl) * Kd + k0 + kc * 8) = o;
  }
}

// ---------------- V transpose: VT[n][k] = SRC[k][off+n]
__global__ __launch_bounds__(256) void trans_v(const __bf16* __restrict__ SRC,
                                               __bf16* __restrict__ VT,
                                               int str, int off) {
  __shared__ __bf16 t[64 * 72];
  const int tid = threadIdx.x;
  const int n0 = blockIdx.x * 64, k0 = blockIdx.y * 64;
  #pragma unroll
  for (int it = 0; it < 2; ++it) {
    int q = tid + it * 256;
    int r = q >> 3, c8 = q & 7;
    bf16x8 v = *(const bf16x8*)(SRC + (size_t)(k0 + r) * str + off + c8 * 8 + n0);
    int eo = (c8 * 8) ^ (((r >> 3) & 7) * 8);
    *(bf16x8*)&t[r * 72 + eo] = v;
  }
  __syncthreads();
  #pragma unroll
  for (int it = 0; it < 2; ++it) {
    int q = tid + it * 256;
    int nl = q >> 3, kc = q & 7;
    bf16x8 o;
    #pragma unroll
    for (int i = 0; i < 8; ++i)
      o[i] = t[(kc * 8 + i) * 72 + (nl ^ (kc * 8))];
    *(bf16x8*)(VT + (size_t)(n0 + nl) * 4096 + k0 + kc * 8) = o;
  }
}

// ---------------- GEMM: 128x128, BK=32, dbuf LDS, counted-vmcnt pipeline,
// source-swizzled staging. K-loop unrolled x2: buffer offsets are literals
// so all LDS addresses hoist out of the loop (VALU cut). nK must be even.
__global__ __launch_bounds__(256, 3) void gemm_tt(
    const __bf16* __restrict__ A, const void* __restrict__ Araw,
    const __bf16* __restrict__ BT,
    void* __restrict__ Cv, int M, int N, int Kd,
    const int* __restrict__ flag, int cForceBf)
{
  const bool inBf = (*flag > 2048);
  const bool cbf = cForceBf || inBf;
  const __bf16* Ause = inBf ? (const __bf16*)Araw : A;
  __shared__ __bf16 sa[2 * 128 * 32];
  __shared__ __bf16 sb[2 * 128 * 32];
  const int tid = threadIdx.x;
  const int lane = tid & 63, w = tid >> 6;
  const int l15 = lane & 15, lg = lane >> 4;
  const int wr = w >> 1, wc = w & 1;
  const int m0 = blockIdx.y * 128, n0 = blockIdx.x * 128;
  const int lrow = lane >> 2;
  const int lcol = (((lane & 3) ^ (lrow & 3)) * 8);   // source-swizzled col

  f32x4 acc[4][4];
  #pragma unroll
  for (int i = 0; i < 4; ++i)
    #pragma unroll
    for (int j = 0; j < 4; ++j) acc[i][j] = (f32x4)(0.f);

  const __bf16* Ab = Ause + (size_t)(m0 + w * 32 + lrow) * Kd + lcol;
  const __bf16* Bb = BT   + (size_t)(n0 + w * 32 + lrow) * Kd + lcol;
  const int nK = Kd >> 5;               // even for all shapes used here

  // prologue: stage tile 0 into buffer 0
  #pragma unroll
  for (int c = 0; c < 2; ++c) {
    gload_lds16(Ab + (size_t)(16 * c) * Kd, &sa[(w * 2 + c) * 512]);
    gload_lds16(Bb + (size_t)(16 * c) * Kd, &sb[(w * 2 + c) * 512]);
  }

  for (int j = 0; j < nK; j += 2) {
    // ---- sub-iter A: compute tile j (buf0), prefetch j+1 -> buf1 (always valid)
    {
      const int k1 = (j + 1) << 5;
      #pragma unroll
      for (int c = 0; c < 2; ++c) {
        gload_lds16(Ab + (size_t)(16 * c) * Kd + k1, &sa[4096 + (w * 2 + c) * 512]);
        gload_lds16(Bb + (size_t)(16 * c) * Kd + k1, &sb[4096 + (w * 2 + c) * 512]);
      }
      asm volatile("s_waitcnt vmcnt(4)" ::: "memory");
      asm volatile("s_barrier" ::: "memory");
      __builtin_amdgcn_sched_barrier(0);
      bf16x8 af[4], bfr[4];
      #pragma unroll
      for (int i = 0; i < 4; ++i) {
        int row = wr * 64 + i * 16 + l15;
        af[i] = *(const bf16x8*)&sa[row * 32 + ((lg ^ (row & 3)) * 8)];
      }
      #pragma unroll
      for (int jj = 0; jj < 4; ++jj) {
        int row = wc * 64 + jj * 16 + l15;
        bfr[jj] = *(const bf16x8*)&sb[row * 32 + ((lg ^ (row & 3)) * 8)];
      }
      #pragma unroll
      for (int i = 0; i < 4; ++i)
        #pragma unroll
        for (int jj = 0; jj < 4; ++jj)
          acc[i][jj] = mfma16x16x32(af[i], bfr[jj], acc[i][jj]);
      __builtin_amdgcn_sched_barrier(0);
      asm volatile("s_barrier" ::: "memory");
    }
    // ---- sub-iter B: compute tile j+1 (buf1), prefetch j+2 -> buf0
    {
      if (j + 2 < nK) {
        const int k2 = (j + 2) << 5;
        #pragma unroll
        for (int c = 0; c < 2; ++c) {
          gload_lds16(Ab + (size_t)(16 * c) * Kd + k2, &sa[(w * 2 + c) * 512]);
          gload_lds16(Bb + (size_t)(16 * c) * Kd + k2, &sb[(w * 2 + c) * 512]);
        }
        asm volatile("s_waitcnt vmcnt(4)" ::: "memory");
      } else {
        asm volatile("s_waitcnt vmcnt(0)" ::: "memory");
      }
      asm volatile("s_barrier" ::: "memory");
      __builtin_amdgcn_sched_barrier(0);
      bf16x8 af[4], bfr[4];
      #pragma unroll
      for (int i = 0; i < 4; ++i) {
        int row = wr * 64 + i * 16 + l15;
        af[i] = *(const bf16x8*)&sa[4096 + row * 32 + ((lg ^ (row & 3)) * 8)];
      }
      #pragma unroll
      for (int jj = 0; jj < 4; ++jj) {
        int row = wc * 64 + jj * 16 + l15;
        bfr[jj] = *(const bf16x8*)&sb[4096 + row * 32 + ((lg ^ (row & 3)) * 8)];
      }
      #pragma unroll
      for (int i = 0; i < 4; ++i)
        #pragma unroll
        for (int jj = 0; jj < 4; ++jj)
          acc[i][jj] = mfma16x16x32(af[i], bfr[jj], acc[i][jj]);
      __builtin_amdgcn_sched_barrier(0);
      asm volatile("s_barrier" ::: "memory");
    }
  }
  __bf16* Cb = (__bf16*)Cv;
  float*  Cf = (float*)Cv;
  #pragma unroll
  for (int i = 0; i < 4; ++i)
    #pragma unroll
    for (int j = 0; j < 4; ++j)
      #pragma unroll
      for (int r = 0; r < 4; ++r) {
        int row = m0 + wr * 64 + i * 16 + lg * 4 + r;
        int col = n0 + wc * 64 + j * 16 + l15;
        if (cbf) Cb[(size_t)row * N + col] = (__bf16)acc[i][j][r];
        else     Cf[(size_t)row * N + col] = acc[i][j][r];
      }
}

// ---------------- merged RoPE: blocks [0,2048) = Q (QSCALE), rest = K.
__global__ __launch_bounds__(256) void rope2(__bf16* __restrict__ qkv, float qscale)
{
  const int bid = blockIdx.x;
  __bf16* buf; int lognh; float scale; int idx0;
  if (bid < 2048) { buf = qkv;        lognh = 4; scale = qscale; idx0 = bid; }
  else            { buf = qkv + 2048; lognh = 2; scale = 1.0f;  idx0 = bid - 2048; }
  const int idx = idx0 * 256 + threadIdx.x;
  const int g   = idx & 7;
  const int h   = (idx >> 3) & ((1 << lognh) - 1);
  const int row = idx >> (3 + lognh);
  const int t   = row & (S_LEN - 1);
  __bf16* p = buf + (size_t)row * 3072 + h * HDIM + g * 8;
  bf16x8 v0 = *(bf16x8*)(p);
  bf16x8 v1 = *(bf16x8*)(p + 64);
  bf16x8 o0, o1;
  #pragma unroll
  for (int j = 0; j < 8; ++j) {
    int i = g * 8 + j;
    float inv = exp2f(-(float)i * 0.2076205059304601f);
    float ang = (float)t * inv;
    float sn, cs;
    sincosf(ang, &sn, &cs);
    cs *= scale; sn *= scale;
    float x0 = (float)v0[j], x1 = (float)v1[j];
    o0[j] = (__bf16)(x0 * cs - x1 * sn);
    o1[j] = (__bf16)(x1 * cs + x0 * sn);
  }
  *(bf16x8*)(p)      = o0;
  *(bf16x8*)(p + 64) = o1;
}

// ---------------- flash attention (r19/r21 form, measured 84 us): single-
// buffer K/V, pl stride 72, 2-barrier loop + T14 reg-prefetch, mask-split.
__device__ __forceinline__ void sm_fixed(
    f32x4 (&st)[4], float& l,
    __bf16* pls, int l15, int lg, int qglob, int kv0, bool diag,
    bf16x8& pa0, bf16x8& pa1)
{
  float rs = 0.f;
  #pragma unroll
  for (int kt = 0; kt < 4; ++kt) {
    bf16x4 pk;
    #pragma unroll
    for (int r = 0; r < 4; ++r) {
      float s = st[kt][r] - 16.f;
      if (diag && (kv0 + kt * 16 + lg * 4 + r > qglob)) s = -1e30f;
      float e = exp2f(s);
      rs += e;
      pk[r] = (__bf16)e;
    }
    *(bf16x4*)&pls[l15 * 72 + kt * 16 + lg * 4] = pk;
  }
  rs += __shfl_xor(rs, 16, 64);
  rs += __shfl_xor(rs, 32, 64);
  l += rs;
  pa0 = *(const bf16x8*)&pls[l15 * 72 + lg * 8];
  pa1 = *(const bf16x8*)&pls[l15 * 72 + 32 + lg * 8];
}

__global__ __launch_bounds__(256, 3) void flash_fwd(
    const __bf16* __restrict__ Q, const __bf16* __restrict__ Km,
    const __bf16* __restrict__ VT, __bf16* __restrict__ O, int qkstr)
{
  __shared__ __bf16 ks[64 * 128];      // K tile [kv][d], XOR-swizzled
  __shared__ __bf16 vt[64 * 128];      // V^T tile [d][kv], XOR-swizzled
  __shared__ __bf16 pl[4][16 * 72];    // per-wave P^T staging, stride 72
  const int id = blockIdx.x;
  const int c8b = id & 255, k = id >> 8;
  const int bh = c8b & 31, g = c8b >> 5;
  const int t = (k == 0) ? g : (k == 1) ? (15 - g) : (k == 2) ? (16 + g) : (31 - g);
  const int b  = bh >> 4, h = bh & 15;
  const int kvh = h >> 2;
  const int tid = threadIdx.x;
  const int lane = tid & 63, w = tid >> 6;
  const int l15 = lane & 15, lg = lane >> 4;
  const int q0 = t * 64 + w * 16;
  const int rbase = tid >> 4, colc = tid & 15;   // K staging coords
  const int vd = tid >> 3, vkc = tid & 7;        // V^T staging coords

  const __bf16* kgb = Km + (size_t)(b * S_LEN) * qkstr + kvh * HDIM + colc * 8;
  const __bf16* vgb = VT + (size_t)(kvh * HDIM + vd) * (2 * S_LEN) + b * S_LEN + vkc * 8;

  bf16x8 aq[4];
  {
    const __bf16* qa = Q + (size_t)(b * S_LEN + q0 + l15) * qkstr + h * HDIM + lg * 8;
    #pragma unroll
    for (int c = 0; c < 4; ++c) aq[c] = *(const bf16x8*)(qa + c * 32);
  }
  f32x4 o[8];
  float l = 0.f;
  #pragma unroll
  for (int c = 0; c < 8; ++c) o[c] = (f32x4)(0.f);

  const int rswz = ((l15 & 7) << 4) ^ (((l15 >> 3) & 1) << 6);

  int kbyt[4], vbyt[4];
  #pragma unroll
  for (int it = 0; it < 4; ++it) {
    int krow = rbase + it * 16;
    kbyt[it] = (krow * 256 + colc * 16) ^ (((krow & 7) << 4) ^ (((krow >> 3) & 1) << 6));
    int vrow = vd + it * 32;
    vbyt[it] = (vrow * 128 + vkc * 16) ^ ((vrow & 7) << 4);
  }

  bf16x8 kreg[4], vreg[4];
  #pragma unroll
  for (int it = 0; it < 4; ++it) {
    kreg[it] = *(const bf16x8*)(kgb + (size_t)(rbase + it * 16) * qkstr);
    vreg[it] = *(const bf16x8*)(vgb + (size_t)(it * 32) * (2 * S_LEN));
  }

  for (int j = 0; j <= t; ++j) {
    const int kv0 = j * 64;
    if (j) __syncthreads();
    #pragma unroll
    for (int it = 0; it < 4; ++it) {
      *(bf16x8*)((char*)ks + kbyt[it]) = kreg[it];
      *(bf16x8*)((char*)vt + vbyt[it]) = vreg[it];
    }
    __syncthreads();
    if (j < t) {
      #pragma unroll
      for (int it = 0; it < 4; ++it) {
        kreg[it] = *(const bf16x8*)(kgb + (size_t)(kv0 + 64 + rbase + it * 16) * qkstr);
        vreg[it] = *(const bf16x8*)(vgb + (size_t)(it * 32) * (2 * S_LEN) + kv0 + 64);
      }
    }

    f32x4 st[4];
    __builtin_amdgcn_s_setprio(1);
    #pragma unroll
    for (int kt = 0; kt < 4; ++kt) {
      st[kt] = (f32x4)(0.f);
      #pragma unroll
      for (int c = 0; c < 4; ++c) {
        int byt = ((kt * 16 + l15) * 256 + c * 64 + lg * 16) ^ rswz;
        bf16x8 kf = *(const bf16x8*)((const char*)ks + byt);
        st[kt] = mfma16x16x32(kf, aq[c], st[kt]);
      }
    }
    __builtin_amdgcn_s_setprio(0);

    bf16x8 pa0, pa1;
    if (j == t)
      sm_fixed(st, l, &pl[w][0], l15, lg, q0 + l15, kv0, true, pa0, pa1);
    else
      sm_fixed(st, l, &pl[w][0], l15, lg, q0 + l15, kv0, false, pa0, pa1);

    __builtin_amdgcn_s_setprio(1);
    #pragma unroll
    for (int c = 0; c < 8; ++c) {
      int d0 = c * 16 + l15;
      int byt0 = (d0 * 128 + lg * 16) ^ ((d0 & 7) << 4);
      int byt1 = (d0 * 128 + lg * 16 + 64) ^ ((d0 & 7) << 4);
      bf16x8 bv0 = *(const bf16x8*)((const char*)vt + byt0);
      bf16x8 bv1 = *(const bf16x8*)((const char*)vt + byt1);
      o[c] = mfma16x16x32(pa0, bv0, o[c]);
      o[c] = mfma16x16x32(pa1, bv1, o[c]);
    }
    __builtin_amdgcn_s_setprio(0);
  }

  float lo[4];
  #pragma unroll
  for (int r = 0; r < 4; ++r) lo[r] = __shfl(l, lg * 4 + r, 64);
  #pragma unroll
  for (int c = 0; c < 8; ++c)
    #pragma unroll
    for (int r = 0; r < 4; ++r)
      O[(size_t)(b * S_LEN + q0 + lg * 4 + r) * EDIM + h * HDIM + c * 16 + l15] =
          (__bf16)(o[c][r] / lo[r]);
}

extern "C" void kernel_launch(void* const* d_in, const int* in_sizes, int n_in,
                              void* d_out, int out_size, void* d_ws, size_t ws_size,
                              hipStream_t stream) {
  const void* x  = d_in[0];
  const void* wq = d_in[1];
  const void* wk = d_in[2];
  const void* wv = d_in[3];
  const void* wo = d_in[4];
  char* ws = (char*)d_ws;
  int*    flagp = (int*)ws;
  __bf16* QKVw = (__bf16*)(ws + 1024);                       // 24 MB [4096][3072]
  __bf16* R4   = (__bf16*)(ws + 1024 + (24u << 20));         // 16 MB: xb then Ow
  __bf16* R5   = (__bf16*)(ws + 1024 + (40u << 20));         // 12 MB: B^T scratch
  __bf16* VwT  = R5 + (size_t)2048 * 2048;                   //  4 MB [512][4096]

  const float QSCALE = 1.4426950408889634f * 0.08838834764831845f; // log2e/sqrt(128)
  dim3 blk(256);
  probe_dtype<<<1, blk, 0, stream>>>((const unsigned int*)x, flagp);
  xconv<<<4096, blk, 0, stream>>>(x, R4, flagp);             // no-op if input bf16

  // fused QKV projection: BT = [wq^T; wk^T; wv^T] [3072][2048]
  trans_w3<<<dim3(48, 32), blk, 0, stream>>>(wq, wk, wv, R5, flagp);
  gemm_tt<<<dim3(24, 32), blk, 0, stream>>>(R4, x, R5, QKVw, 4096, 3072, 2048, flagp, 1);

  rope2<<<2560, blk, 0, stream>>>(QKVw, QSCALE);                     // Q+K, one launch
  trans_v<<<dim3(8, 64), blk, 0, stream>>>(QKVw, VwT, 3072, 2560);   // V^T [512][4096]

  trans_w<<<dim3(32, 32), blk, 0, stream>>>(wo, R5, EDIM, EDIM, flagp);
  flash_fwd<<<dim3(1024), blk, 0, stream>>>(QKVw, QKVw + 2048, VwT, R4, 3072); // Ow = R4
  gemm_tt<<<dim3(16, 32), blk, 0, stream>>>(R4, R4, R5, d_out, 4096, 2048, 2048, flagp, 0);
}